// Round 6
// baseline (2225.175 us; speedup 1.0000x reference)
//
#include <hip/hip_runtime.h>

typedef __bf16 bf16_t;
typedef bf16_t bf16x8 __attribute__((ext_vector_type(8)));
typedef unsigned int u32x4 __attribute__((ext_vector_type(4)));
typedef float f32x4 __attribute__((ext_vector_type(4)));

#define DEVINL __device__ __forceinline__

constexpr int N_PTS = 65536;

DEVINL ushort f2bs(float x) {
  unsigned u = __builtin_bit_cast(unsigned, x);
  return (ushort)((u + 0x7fffu + ((u >> 16) & 1u)) >> 16);  // RNE
}
DEVINL float bs2f(ushort s) {
  unsigned u = ((unsigned)s) << 16;
  return __builtin_bit_cast(float, u);
}

// ---------------- prep: data f32 -> bf16 ----------------
__global__ __launch_bounds__(256) void cvt_data_k(const float* __restrict__ in,
                                                  ushort* __restrict__ out) {
  int i = (blockIdx.x * 256 + threadIdx.x) * 4;
  float4 v = *reinterpret_cast<const float4*>(in + i);
  ushort4 o;
  o.x = f2bs(v.x); o.y = f2bs(v.y); o.z = f2bs(v.z); o.w = f2bs(v.w);
  *reinterpret_cast<ushort4*>(out + i) = o;
}

// ---------------- prep: transpose weights to (N,K) bf16 ----------------
__global__ __launch_bounds__(256) void prep_w_k(const float* __restrict__ Wqkv,
                                                const float* __restrict__ Wproj,
                                                ushort* __restrict__ WqkvT,
                                                ushort* __restrict__ WprojT) {
  int t = blockIdx.x * 256 + threadIdx.x;  // < 262144
  if (t < 196608) {                        // Wqkv: 128 k-groups x 1536 n
    int kg = t / 1536, n = t - kg * 1536;
    int k0 = kg * 4;
    ushort4 o;
    o.x = f2bs(Wqkv[(size_t)(k0 + 0) * 1536 + n]);
    o.y = f2bs(Wqkv[(size_t)(k0 + 1) * 1536 + n]);
    o.z = f2bs(Wqkv[(size_t)(k0 + 2) * 1536 + n]);
    o.w = f2bs(Wqkv[(size_t)(k0 + 3) * 1536 + n]);
    *reinterpret_cast<ushort4*>(&WqkvT[n * 512 + k0]) = o;
  } else {
    int t2 = t - 196608;                   // Wproj: 128 k-groups x 512 n
    int kg = t2 >> 9, n = t2 & 511;
    int k0 = kg * 4;
    ushort4 o;
    o.x = f2bs(Wproj[(size_t)(k0 + 0) * 512 + n]);
    o.y = f2bs(Wproj[(size_t)(k0 + 1) * 512 + n]);
    o.z = f2bs(Wproj[(size_t)(k0 + 2) * 512 + n]);
    o.w = f2bs(Wproj[(size_t)(k0 + 3) * 512 + n]);
    *reinterpret_cast<ushort4*>(&WprojT[n * 512 + k0]) = o;
  }
}

// ---------------- fused qkv-GEMM + RoPE + windowed attention ----------------
// Block = (window-group g, head h), h = bid&7 so each XCD's L2 keeps one head's
// 196KB weight slice. 4 waves, 256 threads.
//   phase 1: GEMM  qkv[112 rows][192 cols] = data[96g-12 .. 96g+100) @ Wqkv(head h)
//            wave w owns col-frags {f0,f1,fv} = {(w>>1)*4+(w&1), +2, 8+w} so the
//            RoPE pair (d, d+32) lives in frags f0,f1 of the SAME lane.
//   phase 2: +bias, RoPE(q,k), pad rows (n<0 -> -1.0, n>=N -> 0.0), dump bf16 to LDS
//   phase 3: wave w = window dw=w: 24x24 scores + mask, softmax, PV, packed-dword out
__global__ __launch_bounds__(256) void fused_qkv_attn_k(
    const ushort* __restrict__ dat,    // N x 512 bf16
    const ushort* __restrict__ WqkvT,  // 1536 x 512 bf16
    const float* __restrict__ bqkv,    // 1536
    const float* __restrict__ xyz,     // N x 3
    const float* __restrict__ freqs,   // 8 x 32 x 3
    const float* __restrict__ mask,    // 2732 x 24 x 24
    ushort* __restrict__ outa)         // N x 512 bf16
{
  // LDS: staging (A dbuf 14336 + B dbuf 24576 = 38912) overlapped by qkv 112x202x2=45248; sS after.
  __shared__ alignas(16) char lds[45248 + 9600];
  ushort* sAu = (ushort*)lds;                    // [2][112*32]
  ushort* sBu = (ushort*)(lds + 14336);          // [2][192*32]
  ushort* sQ  = (ushort*)lds;                    // [112][202]  (phase 2+)
  float*  sS  = (float*)(lds + 45248);           // [4][24][25]

  const int bid = blockIdx.x;
  const int h = bid & 7, g = bid >> 3;
  const int tid = threadIdx.x, lane = tid & 63, w = tid >> 6;
  const int row0 = g * 96 - 12;

  // ---- staging addressing (A: 448 16B-chunks, B: 768) ----
  const int rA1 = tid >> 2,          kA1 = tid & 3;
  const int rA2 = (tid + 256) >> 2,  kA2 = tid & 3;   // (tid+256)&3 == tid&3
  const bool hasA2 = tid < 192;
  const int srcA1 = min(max(row0 + rA1, 0), N_PTS - 1);
  const int srcA2 = min(max(row0 + rA2, 0), N_PTS - 1);
  const ushort* gA1 = dat + (size_t)srcA1 * 512 + kA1 * 8;
  const ushort* gA2 = dat + (size_t)srcA2 * 512 + kA2 * 8;
  const int wA1 = rA1 * 32 + ((kA1 ^ ((rA1 >> 1) & 3)) << 3);
  const int wA2 = rA2 * 32 + ((kA2 ^ ((rA2 >> 1) & 3)) << 3);

  const ushort* gB[3]; int wB[3];
#pragma unroll
  for (int i = 0; i < 3; ++i) {
    const int c = tid + 256 * i;
    const int br = c >> 2, kc = c & 3;
    const int seg = br >> 6, loc = br & 63;
    gB[i] = WqkvT + (size_t)(seg * 512 + h * 64 + loc) * 512 + kc * 8;
    wB[i] = br * 32 + ((kc ^ ((br >> 1) & 3)) << 3);
  }

  const int x15 = lane & 15;
  const int krow = (lane >> 4) * 8;
  const int swz8 = ((x15 >> 1) & 3) << 3;
  const int f0 = (w >> 1) * 4 + (w & 1), f1 = f0 + 2, fv = 8 + w;

  f32x4 acc[7][3] = {};

  // ---- prologue: stage k-chunk 0 into buffer 0 ----
  {
    u32x4 a1 = *reinterpret_cast<const u32x4*>(gA1);
    u32x4 a2 = *reinterpret_cast<const u32x4*>(gA2);
    u32x4 b0 = *reinterpret_cast<const u32x4*>(gB[0]);
    u32x4 b1 = *reinterpret_cast<const u32x4*>(gB[1]);
    u32x4 b2 = *reinterpret_cast<const u32x4*>(gB[2]);
    *reinterpret_cast<u32x4*>(&sAu[wA1]) = a1;
    if (hasA2) *reinterpret_cast<u32x4*>(&sAu[wA2]) = a2;
    *reinterpret_cast<u32x4*>(&sBu[wB[0]]) = b0;
    *reinterpret_cast<u32x4*>(&sBu[wB[1]]) = b1;
    *reinterpret_cast<u32x4*>(&sBu[wB[2]]) = b2;
  }
  __syncthreads();

  int cur = 0;
#pragma unroll 1
  for (int t = 0; t < 16; ++t) {
    u32x4 nA1, nA2, nB0, nB1, nB2;
    if (t < 15) {
      const int kb = (t + 1) * 32;
      nA1 = *reinterpret_cast<const u32x4*>(gA1 + kb);
      nA2 = *reinterpret_cast<const u32x4*>(gA2 + kb);
      nB0 = *reinterpret_cast<const u32x4*>(gB[0] + kb);
      nB1 = *reinterpret_cast<const u32x4*>(gB[1] + kb);
      nB2 = *reinterpret_cast<const u32x4*>(gB[2] + kb);
    }

    const ushort* sAc = sAu + cur * 3584;
    const ushort* sBc = sBu + cur * 6144;
    bf16x8 bf0 = *reinterpret_cast<const bf16x8*>(&sBc[(f0 * 16 + x15) * 32 + (krow ^ swz8)]);
    bf16x8 bf1 = *reinterpret_cast<const bf16x8*>(&sBc[(f1 * 16 + x15) * 32 + (krow ^ swz8)]);
    bf16x8 bfv = *reinterpret_cast<const bf16x8*>(&sBc[(fv * 16 + x15) * 32 + (krow ^ swz8)]);
#pragma unroll
    for (int fi = 0; fi < 7; ++fi) {
      bf16x8 af = *reinterpret_cast<const bf16x8*>(&sAc[(fi * 16 + x15) * 32 + (krow ^ swz8)]);
      acc[fi][0] = __builtin_amdgcn_mfma_f32_16x16x32_bf16(af, bf0, acc[fi][0], 0, 0, 0);
      acc[fi][1] = __builtin_amdgcn_mfma_f32_16x16x32_bf16(af, bf1, acc[fi][1], 0, 0, 0);
      acc[fi][2] = __builtin_amdgcn_mfma_f32_16x16x32_bf16(af, bfv, acc[fi][2], 0, 0, 0);
    }

    if (t < 15) {
      const int nxt = cur ^ 1;
      ushort* dA = sAu + nxt * 3584;
      ushort* dB = sBu + nxt * 6144;
      __syncthreads();  // all frag reads of 'cur' AND previous writes settled
      *reinterpret_cast<u32x4*>(&dA[wA1]) = nA1;
      if (hasA2) *reinterpret_cast<u32x4*>(&dA[wA2]) = nA2;
      *reinterpret_cast<u32x4*>(&dB[wB[0]]) = nB0;
      *reinterpret_cast<u32x4*>(&dB[wB[1]]) = nB1;
      *reinterpret_cast<u32x4*>(&dB[wB[2]]) = nB2;
      __syncthreads();
      cur = nxt;
    }
  }
  __syncthreads();  // GEMM reads done; staging LDS may now be overwritten by sQ

  // ---- phase 2: bias + RoPE + pad, dump bf16 qkv to sQ[112][202] ----
  {
    const int cl = x15, rb = (lane >> 4) * 4;
    const float b0 = bqkv[(f0 >> 2) * 512 + h * 64 + (f0 & 3) * 16 + cl];
    const float b1 = bqkv[(f1 >> 2) * 512 + h * 64 + (f1 & 3) * 16 + cl];
    const float bv = bqkv[1024 + h * 64 + w * 16 + cl];
    const int dlo = (f0 & 3) * 16 + cl;          // freq index p in [0,32)
    const float* fp = freqs + (h * 32 + dlo) * 3;
    const float fx = fp[0], fy = fp[1], fz = fp[2];
#pragma unroll
    for (int fi = 0; fi < 7; ++fi) {
#pragma unroll
      for (int r = 0; r < 4; ++r) {
        const int m = fi * 16 + rb + r;          // 0..111
        const int n = row0 + m;
        ushort* qr = sQ + m * 202;
        if (n < 0) {
          qr[f0 * 16 + cl] = 0xBF80; qr[f1 * 16 + cl] = 0xBF80; qr[fv * 16 + cl] = 0xBF80;
        } else if (n >= N_PTS) {
          qr[f0 * 16 + cl] = 0; qr[f1 * 16 + cl] = 0; qr[fv * 16 + cl] = 0;
        } else {
          const float lo = acc[fi][0][r] + b0;
          const float hi = acc[fi][1][r] + b1;
          const float vv = acc[fi][2][r] + bv;
          const float x0 = xyz[3 * n + 0], x1 = xyz[3 * n + 1], x2 = xyz[3 * n + 2];
          const float th = x0 * fx + x1 * fy + x2 * fz;
          const float s = sinf(th), c = cosf(th);
          qr[f0 * 16 + cl] = f2bs(lo * c - hi * s);
          qr[f1 * 16 + cl] = f2bs(lo * s + hi * c);
          qr[fv * 16 + cl] = f2bs(vv);
        }
      }
    }
  }
  __syncthreads();

  // ---- phase 3: attention, wave w = window (g, dw=w), head h ----
  const int b = g * 4 + w;
  float* sSw = sS + w * 600;  // [24][25]
  for (int j = 0; j < 9; ++j) {
    const int e = j * 64 + lane;                 // < 576
    const int qi = e / 24, ki = e - qi * 24;
    const ushort* qr = sQ + (w + 4 * qi) * 202;
    const ushort* kr = sQ + (w + 4 * ki) * 202 + 64;
    float s = 0.f;
#pragma unroll
    for (int d = 0; d < 64; ++d) s = fmaf(bs2f(qr[d]), bs2f(kr[d]), s);
    sSw[qi * 25 + ki] = s * 0.125f + mask[(size_t)b * 576 + e];
  }
  __syncthreads();

  if (lane < 24) {  // per-row softmax; masked (-1000) underflow to 0 in expf
    float mx = -3.4e38f;
#pragma unroll
    for (int k2 = 0; k2 < 24; ++k2) mx = fmaxf(mx, sSw[lane * 25 + k2]);
    float sum = 0.f;
#pragma unroll
    for (int k2 = 0; k2 < 24; ++k2) { float tv = expf(sSw[lane * 25 + k2] - mx); sum += tv; sSw[lane * 25 + k2] = tv; }
    float inv = 1.0f / sum;
#pragma unroll
    for (int k2 = 0; k2 < 24; ++k2) sSw[lane * 25 + k2] *= inv;
  }
  __syncthreads();

  for (int qi = 0; qi < 24; ++qi) {
    const int n = row0 + w + 4 * qi;
    if (n < 0 || n >= N_PTS) continue;           // wave-uniform
    float o = 0.f;
#pragma unroll
    for (int ki = 0; ki < 24; ++ki)
      o = fmaf(sSw[qi * 25 + ki], bs2f(sQ[(w + 4 * ki) * 202 + 128 + lane]), o);
    // pack 2 bf16 per lane -> dword stores (32 lanes x 4B = contiguous 128B)
    const float oe = __shfl(o, (lane & 31) * 2);
    const float oo = __shfl(o, (lane & 31) * 2 + 1);
    if (lane < 32) {
      const unsigned pk = (unsigned)f2bs(oe) | ((unsigned)f2bs(oo) << 16);
      ((unsigned*)outa)[(size_t)n * 256 + h * 32 + lane] = pk;
    }
  }
}

// ---------------- output GEMM: out = attn @ WprojT^T + bproj (f32 out) ----------------
__global__ __launch_bounds__(256) void gemm2_k(
    const ushort* __restrict__ A,    // N x 512 bf16 (attn out)
    const ushort* __restrict__ Bt,   // 512 x 512 bf16
    const float* __restrict__ bias,  // 512
    float* __restrict__ Of)          // N x 512 f32
{
  __shared__ alignas(16) ushort sA[2][128 * 32];
  __shared__ alignas(16) ushort sB[2][128 * 32];
  const int tid  = threadIdx.x;
  const int lane = tid & 63;
  const int w    = tid >> 6;
  const int wm = w >> 1, wn = w & 1;

  const int cpx = (int)gridDim.x >> 3;
  const int bid = (int)blockIdx.x;
  const int wid = (bid & 7) * cpx + (bid >> 3);
  const int bxi = wid >> 2;
  const int byi = wid & 3;
  const int tileM = bxi * 128;
  const int tileN = byi * 128;

  f32x4 acc[4][4] = {};

  const int r0 = tid >> 2;
  const int c0 = tid & 3;
  const ushort* gA0 = A  + (size_t)(tileM + r0) * 512 + c0 * 8;
  const ushort* gB0 = Bt + (size_t)(tileN + r0) * 512 + c0 * 8;
  const ushort* gA1 = gA0 + 64 * 512;
  const ushort* gB1 = gB0 + 64 * 512;
  const int key = (r0 >> 1) & 3;
  const int xw0 = r0 * 32 + ((c0 ^ key) << 3);
  const int xw1 = (r0 + 64) * 32 + ((c0 ^ key) << 3);

  const int krow = (lane >> 4) * 8;
  const int swz8 = (((lane & 15) >> 1) & 3) << 3;

  {
    u32x4 pA0 = *reinterpret_cast<const u32x4*>(gA0);
    u32x4 pB0 = *reinterpret_cast<const u32x4*>(gB0);
    u32x4 pA1 = *reinterpret_cast<const u32x4*>(gA1);
    u32x4 pB1 = *reinterpret_cast<const u32x4*>(gB1);
    *reinterpret_cast<u32x4*>(&sA[0][xw0]) = pA0;
    *reinterpret_cast<u32x4*>(&sB[0][xw0]) = pB0;
    *reinterpret_cast<u32x4*>(&sA[0][xw1]) = pA1;
    *reinterpret_cast<u32x4*>(&sB[0][xw1]) = pB1;
  }
  __syncthreads();

  int cur = 0;
#pragma unroll 1
  for (int t = 0; t < 16; ++t) {
    u32x4 nA0, nB0, nA1, nB1;
    if (t < 15) {
      const int k0 = (t + 1) * 32;
      nA0 = *reinterpret_cast<const u32x4*>(gA0 + k0);
      nB0 = *reinterpret_cast<const u32x4*>(gB0 + k0);
      nA1 = *reinterpret_cast<const u32x4*>(gA1 + k0);
      nB1 = *reinterpret_cast<const u32x4*>(gB1 + k0);
    }

    bf16x8 af[4], bfr[4];
#pragma unroll
    for (int i = 0; i < 4; ++i) {
      const int rA = wm * 64 + i * 16 + (lane & 15);
      const int rB = wn * 64 + i * 16 + (lane & 15);
      af[i]  = *reinterpret_cast<const bf16x8*>(&sA[cur][rA * 32 + (krow ^ swz8)]);
      bfr[i] = *reinterpret_cast<const bf16x8*>(&sB[cur][rB * 32 + (krow ^ swz8)]);
    }
#pragma unroll
    for (int i = 0; i < 4; ++i)
#pragma unroll
      for (int j = 0; j < 4; ++j)
        acc[i][j] = __builtin_amdgcn_mfma_f32_16x16x32_bf16(af[i], bfr[j], acc[i][j], 0, 0, 0);

    if (t < 15) {
      const int nxt = cur ^ 1;
      *reinterpret_cast<u32x4*>(&sA[nxt][xw0]) = nA0;
      *reinterpret_cast<u32x4*>(&sB[nxt][xw0]) = nB0;
      *reinterpret_cast<u32x4*>(&sA[nxt][xw1]) = nA1;
      *reinterpret_cast<u32x4*>(&sB[nxt][xw1]) = nB1;
      __syncthreads();
      cur = nxt;
    }
  }

  const int cl   = lane & 15;
  const int rb   = (lane >> 4) * 4;
  const int wrow = tileM + wm * 64;
  const int wcol = tileN + wn * 64;
  float bsv[4];
#pragma unroll
  for (int nf = 0; nf < 4; ++nf) bsv[nf] = bias[wcol + nf * 16 + cl];

#pragma unroll
  for (int mf = 0; mf < 4; ++mf)
#pragma unroll
    for (int r = 0; r < 4; ++r) {
      const int m = wrow + mf * 16 + rb + r;
      float* orow = Of + (size_t)m * 512 + wcol;
#pragma unroll
      for (int nf = 0; nf < 4; ++nf) orow[nf * 16 + cl] = acc[mf][nf][r] + bsv[nf];
    }
}

extern "C" void kernel_launch(void* const* d_in, const int* in_sizes, int n_in,
                              void* d_out, int out_size, void* d_ws, size_t ws_size,
                              hipStream_t stream) {
  const float* data  = (const float*)d_in[0];
  const float* xyz   = (const float*)d_in[1];
  const float* mask  = (const float*)d_in[2];
  const float* Wqkv  = (const float*)d_in[3];
  const float* bqkv  = (const float*)d_in[4];
  const float* Wproj = (const float*)d_in[5];
  const float* bproj = (const float*)d_in[6];
  const float* freqs = (const float*)d_in[7];
  float* out = (float*)d_out;

  char* ws = (char*)d_ws;
  // layout: attn_out (64MB) | dat_bf (64MB) | WqkvT (1.5MB) | WprojT (0.5MB)
  ushort* attn_o = (ushort*)ws;
  ushort* dat_bf = (ushort*)(ws + (size_t)67108864);
  ushort* WqkvT  = (ushort*)(ws + (size_t)134217728);
  ushort* WprojT = (ushort*)(ws + (size_t)135790592);

  cvt_data_k<<<32768, 256, 0, stream>>>(data, dat_bf);
  prep_w_k<<<1024, 256, 0, stream>>>(Wqkv, Wproj, WqkvT, WprojT);
  fused_qkv_attn_k<<<5464, 256, 0, stream>>>(dat_bf, WqkvT, bqkv, xyz, freqs, mask, attn_o);
  gemm2_k<<<2048, 256, 0, stream>>>(attn_o, WprojT, bproj, out);
}

// Round 9
// 2133.346 us; speedup vs baseline: 1.0430x; 1.0430x over previous
//
#include <hip/hip_runtime.h>

typedef __bf16 bf16_t;
typedef bf16_t bf16x8 __attribute__((ext_vector_type(8)));
typedef unsigned int u32x4 __attribute__((ext_vector_type(4)));
typedef float f32x4 __attribute__((ext_vector_type(4)));

#define DEVINL __device__ __forceinline__

constexpr int N_PTS = 65536;

DEVINL ushort f2bs(float x) {
  unsigned u = __builtin_bit_cast(unsigned, x);
  return (ushort)((u + 0x7fffu + ((u >> 16) & 1u)) >> 16);  // RNE
}
DEVINL float bs2f(ushort s) {
  unsigned u = ((unsigned)s) << 16;
  return __builtin_bit_cast(float, u);
}

// ---------------- prep: data f32 -> bf16 ----------------
__global__ __launch_bounds__(256) void cvt_data_k(const float* __restrict__ in,
                                                  ushort* __restrict__ out) {
  int i = (blockIdx.x * 256 + threadIdx.x) * 4;
  float4 v = *reinterpret_cast<const float4*>(in + i);
  ushort4 o;
  o.x = f2bs(v.x); o.y = f2bs(v.y); o.z = f2bs(v.z); o.w = f2bs(v.w);
  *reinterpret_cast<ushort4*>(out + i) = o;
}

// ---------------- prep: transpose weights to (N,K) bf16 ----------------
__global__ __launch_bounds__(256) void prep_w_k(const float* __restrict__ Wqkv,
                                                const float* __restrict__ Wproj,
                                                ushort* __restrict__ WqkvT,
                                                ushort* __restrict__ WprojT) {
  int t = blockIdx.x * 256 + threadIdx.x;  // < 262144
  if (t < 196608) {                        // Wqkv: 128 k-groups x 1536 n
    int kg = t / 1536, n = t - kg * 1536;
    int k0 = kg * 4;
    ushort4 o;
    o.x = f2bs(Wqkv[(size_t)(k0 + 0) * 1536 + n]);
    o.y = f2bs(Wqkv[(size_t)(k0 + 1) * 1536 + n]);
    o.z = f2bs(Wqkv[(size_t)(k0 + 2) * 1536 + n]);
    o.w = f2bs(Wqkv[(size_t)(k0 + 3) * 1536 + n]);
    *reinterpret_cast<ushort4*>(&WqkvT[n * 512 + k0]) = o;
  } else {
    int t2 = t - 196608;                   // Wproj: 128 k-groups x 512 n
    int kg = t2 >> 9, n = t2 & 511;
    int k0 = kg * 4;
    ushort4 o;
    o.x = f2bs(Wproj[(size_t)(k0 + 0) * 512 + n]);
    o.y = f2bs(Wproj[(size_t)(k0 + 1) * 512 + n]);
    o.z = f2bs(Wproj[(size_t)(k0 + 2) * 512 + n]);
    o.w = f2bs(Wproj[(size_t)(k0 + 3) * 512 + n]);
    *reinterpret_cast<ushort4*>(&WprojT[n * 512 + k0]) = o;
  }
}

// ---------------- GEMM (B^T input), K=512, 128x128 tile, reg-staged dbuf ----------------
// Main loop = Round-5's (reg-staged global->VGPR->swizzled ds_write_b128, dbuf,
// verified). Epilogue = Round-4's (rope inline, per-wave LDS transpose, asm
// global_store_dwordx4, window-major rows, verified). No global_load_lds, no
// sub-dword global stores anywhere.
template <int NC, bool ROPE>
__global__ __launch_bounds__(256) void gemm_bt_k(
    const ushort* __restrict__ A,    // M x 512 bf16
    const ushort* __restrict__ Bt,   // NC x 512 bf16
    const float* __restrict__ bias,  // NC
    const float* __restrict__ xyz,   // N x 3 (ROPE only)
    const float* __restrict__ freqs, // 8 x 32 x 3 (ROPE only)
    ushort* __restrict__ Obf,        // bf16 out, window-major rows (ROPE)
    float* __restrict__ Of)          // f32 out (!ROPE)
{
  __shared__ alignas(16) ushort sA[2][128 * 32];
  __shared__ alignas(16) ushort sB[2][128 * 32];
  const int tid  = threadIdx.x;
  const int lane = tid & 63;
  const int w    = tid >> 6;
  const int wm = w >> 1, wn = w & 1;

  constexpr int NBY = NC / 128;
  const int cpx = (int)gridDim.x >> 3;
  const int bid = (int)blockIdx.x;
  const int wid = (bid & 7) * cpx + (bid >> 3);
  const int bxi = wid / NBY;
  const int byi = wid - bxi * NBY;
  const int tileM = bxi * 128;
  const int tileN = byi * 128;

  f32x4 acc[4][4] = {};

  const int r0 = tid >> 2;   // 0..63
  const int c0 = tid & 3;    // k-chunk of 8 bf16
  const ushort* gA0 = A  + (size_t)(tileM + r0) * 512 + c0 * 8;
  const ushort* gB0 = Bt + (size_t)(tileN + r0) * 512 + c0 * 8;
  const ushort* gA1 = gA0 + 64 * 512;
  const ushort* gB1 = gB0 + 64 * 512;
  const int key = (r0 >> 1) & 3;               // same for r0 and r0+64
  const int xw0 = r0 * 32 + ((c0 ^ key) << 3);
  const int xw1 = (r0 + 64) * 32 + ((c0 ^ key) << 3);

  const int krow = (lane >> 4) * 8;
  const int swz8 = (((lane & 15) >> 1) & 3) << 3;

  // prologue: tile 0
  {
    u32x4 pA0 = *reinterpret_cast<const u32x4*>(gA0);
    u32x4 pB0 = *reinterpret_cast<const u32x4*>(gB0);
    u32x4 pA1 = *reinterpret_cast<const u32x4*>(gA1);
    u32x4 pB1 = *reinterpret_cast<const u32x4*>(gB1);
    *reinterpret_cast<u32x4*>(&sA[0][xw0]) = pA0;
    *reinterpret_cast<u32x4*>(&sB[0][xw0]) = pB0;
    *reinterpret_cast<u32x4*>(&sA[0][xw1]) = pA1;
    *reinterpret_cast<u32x4*>(&sB[0][xw1]) = pB1;
  }
  __syncthreads();

  int cur = 0;
#pragma unroll 1
  for (int t = 0; t < 16; ++t) {
    u32x4 nA0, nB0, nA1, nB1;
    if (t < 15) {
      const int k0 = (t + 1) * 32;
      nA0 = *reinterpret_cast<const u32x4*>(gA0 + k0);
      nB0 = *reinterpret_cast<const u32x4*>(gB0 + k0);
      nA1 = *reinterpret_cast<const u32x4*>(gA1 + k0);
      nB1 = *reinterpret_cast<const u32x4*>(gB1 + k0);
    }

    bf16x8 af[4], bfr[4];
#pragma unroll
    for (int i = 0; i < 4; ++i) {
      const int rA = wm * 64 + i * 16 + (lane & 15);
      const int rB = wn * 64 + i * 16 + (lane & 15);
      af[i]  = *reinterpret_cast<const bf16x8*>(&sA[cur][rA * 32 + (krow ^ swz8)]);
      bfr[i] = *reinterpret_cast<const bf16x8*>(&sB[cur][rB * 32 + (krow ^ swz8)]);
    }
#pragma unroll
    for (int i = 0; i < 4; ++i)
#pragma unroll
      for (int j = 0; j < 4; ++j)
        acc[i][j] = __builtin_amdgcn_mfma_f32_16x16x32_bf16(af[i], bfr[j], acc[i][j], 0, 0, 0);

    if (t < 15) {
      const int nxt = cur ^ 1;
      *reinterpret_cast<u32x4*>(&sA[nxt][xw0]) = nA0;
      *reinterpret_cast<u32x4*>(&sB[nxt][xw0]) = nB0;
      *reinterpret_cast<u32x4*>(&sA[nxt][xw1]) = nA1;
      *reinterpret_cast<u32x4*>(&sB[nxt][xw1]) = nB1;
      __syncthreads();
      cur = nxt;
    }
  }

  // epilogue: C frag layout col = lane&15, row = (lane>>4)*4 + reg
  const int cl   = lane & 15;
  const int rb   = (lane >> 4) * 4;
  const int wrow = tileM + wm * 64;
  const int wcol = tileN + wn * 64;
  float bsv[4];
#pragma unroll
  for (int nf = 0; nf < 4; ++nf) bsv[nf] = bias[wcol + nf * 16 + cl];

  if constexpr (ROPE) {
    __shared__ alignas(16) ushort stg[4][16 * 64];
    const int which = wcol >> 9;
    const int h = (wcol >> 6) & 7;
    const float* fp0 = freqs + (h * 32 + cl) * 3;
    const float* fp1 = freqs + (h * 32 + 16 + cl) * 3;
    const float f00 = fp0[0], f01 = fp0[1], f02 = fp0[2];
    const float f10 = fp1[0], f11 = fp1[1], f12 = fp1[2];
    ushort* swg = stg[w];
#pragma unroll
    for (int mf = 0; mf < 4; ++mf) {
      // ---- write phase: rope+bias, swizzled b16 writes into per-wave staging ----
#pragma unroll
      for (int r = 0; r < 4; ++r) {
        const int row = rb + r;             // local row 0..15
        const int m = wrow + mf * 16 + row;
        const int sx = (row & 7) << 3;      // ushort-index XOR swizzle
        ushort* sr = &swg[row * 64];
        if (which < 2) {
          const float x0 = xyz[3 * m + 0], x1 = xyz[3 * m + 1], x2 = xyz[3 * m + 2];
          const float th0 = x0 * f00 + x1 * f01 + x2 * f02;
          const float th1 = x0 * f10 + x1 * f11 + x2 * f12;
          const float s0 = sinf(th0), c0 = cosf(th0);
          const float s1 = sinf(th1), c1 = cosf(th1);
          const float v0 = acc[mf][0][r] + bsv[0];
          const float v1 = acc[mf][1][r] + bsv[1];
          const float v2 = acc[mf][2][r] + bsv[2];
          const float v3 = acc[mf][3][r] + bsv[3];
          sr[(cl)      ^ sx] = f2bs(v0 * c0 - v2 * s0);
          sr[(16 + cl) ^ sx] = f2bs(v1 * c1 - v3 * s1);
          sr[(32 + cl) ^ sx] = f2bs(v0 * s0 + v2 * c0);
          sr[(48 + cl) ^ sx] = f2bs(v1 * s1 + v3 * c1);
        } else {  // v: no rope
#pragma unroll
          for (int nf = 0; nf < 4; ++nf)
            sr[(nf * 16 + cl) ^ sx] = f2bs(acc[mf][nf][r] + bsv[nf]);
        }
      }
      asm volatile("s_waitcnt lgkmcnt(0)" ::: "memory");
      __builtin_amdgcn_sched_barrier(0);
      // ---- read phase: ds_read_b128 -> inline-asm global_store_dwordx4 ----
      {
        const int lrow = lane >> 2;                 // 0..15
        const int m = wrow + mf * 16 + lrow;
        const int a = m + 12;
        const int g96 = a / 96;
        const int rr = a - g96 * 96;
        const int orow = (g96 * 4 + (rr & 3)) * 24 + (rr >> 2);  // window-major row
#pragma unroll
        for (int inst = 0; inst < 2; ++inst) {
          const int chunk = (lane & 3) + inst * 4;  // 8-ushort group 0..7
          u32x4 v = *reinterpret_cast<const u32x4*>(
              &swg[lrow * 64 + ((chunk ^ (lrow & 7)) << 3)]);
          const ushort* p = Obf + (size_t)orow * NC + wcol + chunk * 8;
          asm volatile("global_store_dwordx4 %0, %1, off" :: "v"(p), "v"(v) : "memory");
        }
      }
      __builtin_amdgcn_sched_barrier(0);
    }
  } else {
    // f32 output: dword stores, 16-lane x 4B contiguous segments coalesce fine
#pragma unroll
    for (int mf = 0; mf < 4; ++mf)
#pragma unroll
      for (int r = 0; r < 4; ++r) {
        const int m = wrow + mf * 16 + rb + r;
        float* orow = Of + (size_t)m * NC + wcol;
#pragma unroll
        for (int nf = 0; nf < 4; ++nf) orow[nf * 16 + cl] = acc[mf][nf][r] + bsv[nf];
      }
  }
}

// ---------------- windowed attention: one wave per (window b, head h) ----------------
// qkv is window-major: row b*24+ki holds point n = g*96+dw+4*ki-12 (b=g*4+dw)
__global__ __launch_bounds__(64) void attn_win_k(const ushort* __restrict__ qkv,  // [65568][1536] bf16
                                                 const float* __restrict__ mask,  // B x 24 x 24
                                                 ushort* __restrict__ outa)       // N x 512 bf16 (point-major)
{
  __shared__ float sq[24][68];
  __shared__ float sk[24][68];
  __shared__ float sv[24][68];
  __shared__ float sS[24][25];
  const int bid = blockIdx.x;
  const int b = bid >> 3, h = bid & 7;
  const int g = b >> 2, dw = b & 3;
  const int lane  = threadIdx.x;
  const int nbase = g * 96 + dw - 12;  // + ki*4

  for (int ki = 0; ki < 24; ++ki) {
    int n = nbase + ki * 4;
    float q, k, v;
    if (n < 0) { q = k = v = -1.0f; }                 // head pad rows are -1.0
    else if (n >= N_PTS) { q = k = v = 0.0f; }        // tail pad rows are 0
    else {
      const ushort* p = qkv + (size_t)(b * 24 + ki) * 1536 + h * 64 + lane;
      q = bs2f(p[0]); k = bs2f(p[512]); v = bs2f(p[1024]);
    }
    sq[ki][lane] = q; sk[ki][lane] = k; sv[ki][lane] = v;
  }
  __syncthreads();

  for (int j = 0; j < 9; ++j) {
    int e = j * 64 + lane;
    int qi = e / 24, ki = e - qi * 24;
    float s = 0.f;
#pragma unroll
    for (int d = 0; d < 64; ++d) s = fmaf(sq[qi][d], sk[ki][d], s);
    sS[qi][ki] = s * 0.125f + mask[(size_t)b * 576 + e];
  }
  __syncthreads();

  if (lane < 24) {
    float mx = -3.4e38f;
#pragma unroll
    for (int k2 = 0; k2 < 24; ++k2) mx = fmaxf(mx, sS[lane][k2]);
    float sum = 0.f;
#pragma unroll
    for (int k2 = 0; k2 < 24; ++k2) { float t = expf(sS[lane][k2] - mx); sum += t; sS[lane][k2] = t; }
    float inv = 1.0f / sum;
#pragma unroll
    for (int k2 = 0; k2 < 24; ++k2) sS[lane][k2] *= inv;
  }
  __syncthreads();

  for (int qi = 0; qi < 24; ++qi) {
    int n = nbase + qi * 4;
    if (n < 0 || n >= N_PTS) continue;
    float o = 0.f;
#pragma unroll
    for (int ki = 0; ki < 24; ++ki) o = fmaf(sS[qi][ki], sv[ki][lane], o);
    outa[(size_t)n * 512 + h * 64 + lane] = f2bs(o);
  }
}

extern "C" void kernel_launch(void* const* d_in, const int* in_sizes, int n_in,
                              void* d_out, int out_size, void* d_ws, size_t ws_size,
                              hipStream_t stream) {
  const float* data  = (const float*)d_in[0];
  const float* xyz   = (const float*)d_in[1];
  const float* mask  = (const float*)d_in[2];
  const float* Wqkv  = (const float*)d_in[3];
  const float* bqkv  = (const float*)d_in[4];
  const float* Wproj = (const float*)d_in[5];
  const float* bproj = (const float*)d_in[6];
  const float* freqs = (const float*)d_in[7];
  float* out = (float*)d_out;

  char* ws = (char*)d_ws;
  // layout: qkv window-major 65568 rows x 1536 bf16 (201.4MB) | dat_bf / attn-out (64MB)
  //         | WqkvT (1.5MB) | WprojT (0.5MB)
  ushort* qkv_ws = (ushort*)ws;
  ushort* dat_bf = (ushort*)(ws + (size_t)201424896);
  ushort* WqkvT  = (ushort*)(ws + (size_t)268533760);
  ushort* WprojT = (ushort*)(ws + (size_t)270106624);

  cvt_data_k<<<32768, 256, 0, stream>>>(data, dat_bf);
  prep_w_k<<<1024, 256, 0, stream>>>(Wqkv, Wproj, WqkvT, WprojT);
  gemm_bt_k<1536, true><<<6144, 256, 0, stream>>>(dat_bf, WqkvT, bqkv, xyz, freqs, qkv_ws, nullptr);
  attn_win_k<<<21856, 64, 0, stream>>>(qkv_ws, mask, dat_bf);
  gemm_bt_k<512, false><<<2048, 256, 0, stream>>>(dat_bf, WprojT, bproj, nullptr, nullptr, nullptr, out);
}